// Round 12
// baseline (334.229 us; speedup 1.0000x reference)
//
#include <hip/hip_runtime.h>
#include <hip/hip_bf16.h>
#include <cstdint>

#define NDIM 128
#define KCLAMP 10.0f

using bf16x8 = __attribute__((ext_vector_type(8))) short;
using f32x4  = __attribute__((ext_vector_type(4))) float;
using f32x2  = __attribute__((ext_vector_type(2))) float;

__device__ __forceinline__ uint16_t f2bf(float f) {
    uint32_t u = __float_as_uint(f);
    uint32_t r = (u + 0x7fffu + ((u >> 16) & 1u)) >> 16;   // RNE
    return (uint16_t)r;
}
__device__ __forceinline__ float bf_lo(uint32_t v) { return __uint_as_float(v << 16); }
__device__ __forceinline__ float bf_hi(uint32_t v) { return __uint_as_float(v & 0xffff0000u); }

// ---------------- fused persistent kernel ----------------
// grid = NBLK blocks of 256 thr, exactly co-resident (launch_bounds(256,4) =>
// VGPR<=128 => >=4 blocks/CU; LDS 32KB => 5; min=4; NBLK = 4*256CU = 1024).
// Phase 1: stage W->LDS once; grid-stride {GEMM tiles (64 rows), rowptr chunks}.
// Grid barrier: threadfence + device-scope atomic arrive/spin (bar zeroed by
// hipMemsetAsync each launch).
// Phase 2: proven gather (4 dst/wave slots, 8-deep clamped pipeline) + epilogue.
__global__ __launch_bounds__(256, 4) void k_fused(
        const float* __restrict__ h, const int* __restrict__ odeg,
        const float* __restrict__ W,
        const int* __restrict__ sdst, int E, const int* __restrict__ ssrc,
        const float* __restrict__ bias, const int* __restrict__ ideg,
        uint16_t* __restrict__ trans, int* __restrict__ row_start,
        int* __restrict__ bar, float* __restrict__ out,
        int M, int ndst, int nBlocks, int gemmTiles, int rpChunks) {
    __shared__ uint16_t Ws[NDIM * NDIM];     // 32 KB, B-frag layout
    int tx = threadIdx.x;

    // ---- stage W once: coalesced float4 rows -> transpose-scatter to frag layout
    // Ws[((n*4+s)*64 + lh*16 + ll)*8 + i] = bf16(W[r][c]), r=s*32+lh*8+i, c=n*16+ll
    for (int j = tx; j < NDIM * NDIM / 4; j += 256) {
        float4 w4 = ((const float4*)W)[j];
        int r  = j >> 5;
        int c4 = (j & 31) * 4;
        int s  = r >> 5, lh = (r >> 3) & 3, i = r & 7;
#pragma unroll
        for (int q = 0; q < 4; ++q) {
            int c = c4 + q;
            int n = c >> 4, ll = c & 15;
            float val = (q == 0) ? w4.x : (q == 1) ? w4.y : (q == 2) ? w4.z : w4.w;
            Ws[((n * 4 + s) * 64 + lh * 16 + ll) * 8 + i] = f2bf(val);
        }
    }
    __syncthreads();

    int wave = tx >> 6, lane = tx & 63;
    int g = lane >> 4;

    // ---- phase 1: grid-stride work items ----
    for (int item = blockIdx.x; item < gemmTiles + rpChunks; item += nBlocks) {
        if (item < gemmTiles) {
            int r0 = item * 64 + wave * 16;
            int arow = r0 + (lane & 15);
            if (arow >= M) arow = M - 1;       // clamp loads; stores predicated
            float nrm = rsqrtf(fmaxf((float)odeg[arow], 1.0f));
            const float4* Arow = (const float4*)(h + (size_t)arow * NDIM);

            f32x4 acc[8];
#pragma unroll
            for (int n = 0; n < 8; ++n) acc[n] = (f32x4){0.f, 0.f, 0.f, 0.f};

#pragma unroll
            for (int s = 0; s < 4; ++s) {
                float4 a0 = Arow[s * 8 + g * 2];
                float4 a1 = Arow[s * 8 + g * 2 + 1];
                bf16x8 af;
                af[0] = (short)f2bf(a0.x * nrm);
                af[1] = (short)f2bf(a0.y * nrm);
                af[2] = (short)f2bf(a0.z * nrm);
                af[3] = (short)f2bf(a0.w * nrm);
                af[4] = (short)f2bf(a1.x * nrm);
                af[5] = (short)f2bf(a1.y * nrm);
                af[6] = (short)f2bf(a1.z * nrm);
                af[7] = (short)f2bf(a1.w * nrm);
#pragma unroll
                for (int n = 0; n < 8; ++n) {
                    bf16x8 bfr = *(const bf16x8*)(Ws + (((n * 4 + s) * 64 + lane) << 3));
                    acc[n] = __builtin_amdgcn_mfma_f32_16x16x32_bf16(af, bfr, acc[n], 0, 0, 0);
                }
            }

            int colL = lane & 15;
            int rowbase = r0 + g * 4;
#pragma unroll
            for (int n = 0; n < 8; ++n) {
#pragma unroll
                for (int r = 0; r < 4; ++r) {
                    int row = rowbase + r;
                    if (row < M)
                        trans[(size_t)row * NDIM + n * 16 + colL] = f2bf(acc[n][r]);
                }
            }
        } else {
            int d = (item - gemmTiles) * 256 + tx;   // lower_bound(sdst, d)
            if (d <= ndst) {
                int lo = 0, hi = E;
                while (lo < hi) {
                    int mid = (lo + hi) >> 1;
                    if (sdst[mid] < d) lo = mid + 1; else hi = mid;
                }
                row_start[d] = lo;
            }
        }
    }

    // ---- grid barrier ----
    __syncthreads();
    if (tx == 0) {
        __threadfence();                      // make trans/row_start device-visible
        __hip_atomic_fetch_add(bar, 1, __ATOMIC_ACQ_REL, __HIP_MEMORY_SCOPE_AGENT);
        while (__hip_atomic_load(bar, __ATOMIC_ACQUIRE, __HIP_MEMORY_SCOPE_AGENT) < nBlocks) {
            __builtin_amdgcn_s_sleep(2);
        }
    }
    __syncthreads();

    // ---- phase 2: gather + segment-sum + epilogue ----
    {
        constexpr int U = 8;
        int sub = lane >> 4;           // dst slot 0..3
        int li  = lane & 15;           // 16B chunk within row
        int gwave  = blockIdx.x * 4 + wave;
        int nwaves = nBlocks * 4;

        float4 b0 = ((const float4*)bias)[li * 2];
        float4 b1 = ((const float4*)bias)[li * 2 + 1];

        for (int d0 = gwave * 4; d0 < ndst; d0 += nwaves * 4) {
            int d = d0 + sub;
            int valid = (d < ndst);
            int s = 0, e = 0;
            if (valid) { s = row_start[d]; e = row_start[d + 1]; }
            int elast = (e > s) ? (e - 1) : 0;

            f32x2 acc[4];
#pragma unroll
            for (int k = 0; k < 4; ++k) acc[k] = (f32x2){0.f, 0.f};

            int idxv[U];
#pragma unroll
            for (int u = 0; u < U; ++u) idxv[u] = ssrc[min(s + u, elast)];

            int pos = s;
            while (__any(pos < e)) {
                uint4 v[U];
#pragma unroll
                for (int u = 0; u < U; ++u)
                    v[u] = *(const uint4*)(trans + (size_t)idxv[u] * NDIM + li * 8);

                int npos = pos + U;
#pragma unroll
                for (int u = 0; u < U; ++u) idxv[u] = ssrc[min(npos + u, elast)];

#pragma unroll
                for (int u = 0; u < U; ++u) {
                    if (pos + u < e) {
                        f32x2 t0 = {bf_lo(v[u].x), bf_hi(v[u].x)};
                        f32x2 t1 = {bf_lo(v[u].y), bf_hi(v[u].y)};
                        f32x2 t2 = {bf_lo(v[u].z), bf_hi(v[u].z)};
                        f32x2 t3 = {bf_lo(v[u].w), bf_hi(v[u].w)};
                        acc[0] += t0; acc[1] += t1; acc[2] += t2; acc[3] += t3;
                    }
                }
                pos = npos;
            }

            if (valid) {
                float nrm = rsqrtf(fminf(fmaxf((float)ideg[d], 1.0f), KCLAMP));
                float4 o0, o1;
                o0.x = acc[0][0] * nrm + b0.x;
                o0.y = acc[0][1] * nrm + b0.y;
                o0.z = acc[1][0] * nrm + b0.z;
                o0.w = acc[1][1] * nrm + b0.w;
                o1.x = acc[2][0] * nrm + b1.x;
                o1.y = acc[2][1] * nrm + b1.y;
                o1.z = acc[3][0] * nrm + b1.z;
                o1.w = acc[3][1] * nrm + b1.w;
                ((float4*)out)[(size_t)d * (NDIM / 4) + li * 2]     = o0;
                ((float4*)out)[(size_t)d * (NDIM / 4) + li * 2 + 1] = o1;
            }
        }
    }
}

// ---------------- fallbacks (workspace too small) ----------------
__global__ void k_rowptr(const int* __restrict__ sdst, int E,
                         int* __restrict__ row_start, int ndst) {
    int d = blockIdx.x * blockDim.x + threadIdx.x;
    if (d > ndst) return;
    int lo = 0, hi = E;
    while (lo < hi) {
        int mid = (lo + hi) >> 1;
        if (sdst[mid] < d) lo = mid + 1; else hi = mid;
    }
    row_start[d] = lo;
}

__global__ void k_agg_f32(const float* __restrict__ h, const int* __restrict__ odeg,
                          const int* __restrict__ ssrc, const int* __restrict__ row_start,
                          float* __restrict__ agg, int ndst) {
    int gtid = blockIdx.x * blockDim.x + threadIdx.x;
    int wave = gtid >> 6;
    int lane = threadIdx.x & 63;
    int nwaves = (gridDim.x * blockDim.x) >> 6;
    for (int d = wave; d < ndst; d += nwaves) {
        int s = row_start[d], e = row_start[d + 1];
        float a0 = 0.f, a1 = 0.f;
        for (int i = s; i < e; i++) {
            int s0 = ssrc[i];
            float nrm = rsqrtf(fmaxf((float)odeg[s0], 1.0f));
            float2 v = ((const float2*)h)[(size_t)s0 * (NDIM / 2) + lane];
            a0 += v.x * nrm;
            a1 += v.y * nrm;
        }
        float2 o; o.x = a0; o.y = a1;
        ((float2*)agg)[(size_t)d * (NDIM / 2) + lane] = o;
    }
}

__global__ __launch_bounds__(256) void k_gemm_f32(float* __restrict__ io,
                                                  const float* __restrict__ W,
                                                  const float* __restrict__ bias,
                                                  const int* __restrict__ ideg, int M) {
    __shared__ float Wsf[NDIM][NDIM];
    int tx = threadIdx.x;
    {
        const float4* Wv = (const float4*)W;
        float4* Wsv = (float4*)&Wsf[0][0];
        for (int i = tx; i < NDIM * NDIM / 4; i += 256) Wsv[i] = Wv[i];
    }
    __syncthreads();
    int cg = tx & 31, rg = tx >> 5;
    int r0 = blockIdx.x * 64 + rg * 8, c0 = cg * 4;
    float acc[8][4];
#pragma unroll
    for (int r = 0; r < 8; ++r)
#pragma unroll
        for (int c = 0; c < 4; ++c) acc[r][c] = 0.f;
    for (int k4 = 0; k4 < NDIM / 4; ++k4) {
        float4 wk0 = *(const float4*)&Wsf[4 * k4 + 0][c0];
        float4 wk1 = *(const float4*)&Wsf[4 * k4 + 1][c0];
        float4 wk2 = *(const float4*)&Wsf[4 * k4 + 2][c0];
        float4 wk3 = *(const float4*)&Wsf[4 * k4 + 3][c0];
#pragma unroll
        for (int r = 0; r < 8; ++r) {
            int row = r0 + r;
            if (row < M) {
                float4 a = ((const float4*)io)[(size_t)row * (NDIM / 4) + k4];
                acc[r][0] += a.x * wk0.x + a.y * wk1.x + a.z * wk2.x + a.w * wk3.x;
                acc[r][1] += a.x * wk0.y + a.y * wk1.y + a.z * wk2.y + a.w * wk3.y;
                acc[r][2] += a.x * wk0.z + a.y * wk1.z + a.z * wk2.z + a.w * wk3.z;
                acc[r][3] += a.x * wk0.w + a.y * wk1.w + a.z * wk2.w + a.w * wk3.w;
            }
        }
    }
    __syncthreads();
    float4 b = *(const float4*)&bias[c0];
#pragma unroll
    for (int r = 0; r < 8; ++r) {
        int row = r0 + r;
        if (row < M) {
            float nrm = rsqrtf(fminf(fmaxf((float)ideg[row], 1.0f), KCLAMP));
            float4 o;
            o.x = acc[r][0] * nrm + b.x;
            o.y = acc[r][1] * nrm + b.y;
            o.z = acc[r][2] * nrm + b.z;
            o.w = acc[r][3] * nrm + b.w;
            ((float4*)io)[(size_t)row * (NDIM / 4) + cg] = o;
        }
    }
}

extern "C" void kernel_launch(void* const* d_in, const int* in_sizes, int n_in,
                              void* d_out, int out_size, void* d_ws, size_t ws_size,
                              hipStream_t stream) {
    const float* h_src  = (const float*)d_in[0];
    const float* weight = (const float*)d_in[1];
    const float* bias   = (const float*)d_in[2];
    const int*   ssrc   = (const int*)d_in[3];
    const int*   sdst   = (const int*)d_in[4];
    const int*   odeg   = (const int*)d_in[5];
    const int*   ideg   = (const int*)d_in[6];
    float* out = (float*)d_out;

    int E    = in_sizes[3];
    int nsrc = in_sizes[0] / NDIM;
    int ndst = out_size / NDIM;

    // ws layout: [0, 1MB-256) row_start ; bar @ 1MB-256 ; trans @ 1MB
    int*      row_start = (int*)d_ws;
    int*      bar   = (int*)((char*)d_ws + ((size_t)1 << 20) - 256);
    uint16_t* trans = (uint16_t*)((char*)d_ws + ((size_t)1 << 20));
    size_t need = ((size_t)1 << 20) + (size_t)nsrc * NDIM * 2;

    if (ws_size >= need && (size_t)(ndst + 2) * 4 < (((size_t)1 << 20) - 256)) {
        const int NBLK = 1024;                // 4 blocks/CU x 256 CU, co-resident
        int gemmTiles = (nsrc + 63) / 64;
        int rpChunks  = (ndst + 1 + 255) / 256;
        hipMemsetAsync(bar, 0, sizeof(int), stream);
        k_fused<<<NBLK, 256, 0, stream>>>(
            h_src, odeg, weight, sdst, E, ssrc, bias, ideg,
            trans, row_start, bar, out, nsrc, ndst, NBLK, gemmTiles, rpChunks);
    } else {
        k_rowptr<<<(ndst + 1 + 255) / 256, 256, 0, stream>>>(sdst, E, row_start, ndst);
        k_agg_f32<<<2048, 256, 0, stream>>>(h_src, odeg, ssrc, row_start, out, ndst);
        k_gemm_f32<<<(ndst + 63) / 64, 256, 0, stream>>>(out, weight, bias, ideg, ndst);
    }
}

// Round 14
// 73.076 us; speedup vs baseline: 4.5737x; 4.5737x over previous
//
#include <hip/hip_runtime.h>
#include <hip/hip_bf16.h>
#include <cstdint>

#define NDIM 128
#define KCLAMP 10.0f

using bf16x8 = __attribute__((ext_vector_type(8))) short;
using f32x4  = __attribute__((ext_vector_type(4))) float;
using f32x2  = __attribute__((ext_vector_type(2))) float;

__device__ __forceinline__ uint16_t f2bf(float f) {
    uint32_t u = __float_as_uint(f);
    uint32_t r = (u + 0x7fffu + ((u >> 16) & 1u)) >> 16;   // RNE
    return (uint16_t)r;
}
__device__ __forceinline__ float bf_lo(uint32_t v) { return __uint_as_float(v << 16); }
__device__ __forceinline__ float bf_hi(uint32_t v) { return __uint_as_float(v & 0xffff0000u); }

// ---------------- k1: trans = bf16((h * norm_src) @ W)  +  rowptr role ----------------
// GEMM blocks [0, gemmBlocks): 512 thr = 8 waves, 128 rows/block.
// Each block stages W itself: coalesced float4 reads of row-major W, transpose-
// scatter into the MFMA B-frag LDS layout (u16 writes, 2-way bank aliasing = free).
// A-fragments straight from global f32 h. rowptr blocks follow in the same grid.
// NOTE: plain (cached) stores only — nontemporal stores break the harness's
// poison/replay protocol (stale L2 lines serve 0xAA after nt writes bypass them).
__global__ __launch_bounds__(512) void k1_gemm(
        const float* __restrict__ h, const int* __restrict__ odeg,
        const float* __restrict__ W, uint16_t* __restrict__ trans, int M,
        const int* __restrict__ sdst, int E, int* __restrict__ row_start, int ndst,
        int gemmBlocks) {
    int b = blockIdx.x;
    int tx = threadIdx.x;

    if (b >= gemmBlocks) {                 // ---- rowptr role ----
        int d = (b - gemmBlocks) * 512 + tx;
        if (d > ndst) return;
        int lo = 0, hi = E;
        while (lo < hi) {
            int mid = (lo + hi) >> 1;
            if (sdst[mid] < d) lo = mid + 1; else hi = mid;
        }
        row_start[d] = lo;
        return;
    }

    __shared__ uint16_t Ws[NDIM * NDIM];     // 32 KB, B-frag layout
    // stage W: Ws[((n*4+s)*64 + lh*16 + ll)*8 + i] = bf16(W[r][c]),
    //          r = s*32 + lh*8 + i, c = n*16 + ll
    for (int j = tx; j < NDIM * NDIM / 4; j += 512) {
        float4 w4 = ((const float4*)W)[j];
        int r  = j >> 5;
        int c4 = (j & 31) * 4;
        int s  = r >> 5, lh = (r >> 3) & 3, i = r & 7;
#pragma unroll
        for (int q = 0; q < 4; ++q) {
            int c = c4 + q;
            int n = c >> 4, ll = c & 15;
            int off = ((n * 4 + s) * 64 + lh * 16 + ll) * 8 + i;
            float val = (q == 0) ? w4.x : (q == 1) ? w4.y : (q == 2) ? w4.z : w4.w;
            Ws[off] = f2bf(val);
        }
    }
    __syncthreads();

    int wave = tx >> 6, lane = tx & 63;
    int g = lane >> 4;
    int r0 = b * 128 + wave * 16;
    int arow = r0 + (lane & 15);
    if (arow >= M) arow = M - 1;             // clamp loads; stores predicated
    float nrm = rsqrtf(fmaxf((float)odeg[arow], 1.0f));
    const float4* Arow = (const float4*)(h + (size_t)arow * NDIM);

    f32x4 acc[8];
#pragma unroll
    for (int n = 0; n < 8; ++n) acc[n] = (f32x4){0.f, 0.f, 0.f, 0.f};

#pragma unroll
    for (int s = 0; s < 4; ++s) {
        float4 a0 = Arow[s * 8 + g * 2];     // k = s*32+g*8 .. +3
        float4 a1 = Arow[s * 8 + g * 2 + 1]; // k = s*32+g*8+4 .. +7
        bf16x8 af;
        af[0] = (short)f2bf(a0.x * nrm);
        af[1] = (short)f2bf(a0.y * nrm);
        af[2] = (short)f2bf(a0.z * nrm);
        af[3] = (short)f2bf(a0.w * nrm);
        af[4] = (short)f2bf(a1.x * nrm);
        af[5] = (short)f2bf(a1.y * nrm);
        af[6] = (short)f2bf(a1.z * nrm);
        af[7] = (short)f2bf(a1.w * nrm);
#pragma unroll
        for (int n = 0; n < 8; ++n) {
            bf16x8 bfr = *(const bf16x8*)(Ws + (((n * 4 + s) * 64 + lane) << 3));
            acc[n] = __builtin_amdgcn_mfma_f32_16x16x32_bf16(af, bfr, acc[n], 0, 0, 0);
        }
    }

    int colL = lane & 15;
    int rowbase = r0 + g * 4;
#pragma unroll
    for (int n = 0; n < 8; ++n) {
#pragma unroll
        for (int r = 0; r < 4; ++r) {
            int row = rowbase + r;
            if (row < M)
                trans[(size_t)row * NDIM + n * 16 + colL] = f2bf(acc[n][r]);
        }
    }
}

// ---------------- k2: pure gather + segment-sum + epilogue (round-7/10/11 proven) ----------------
// 4 dst segments per wave (one per 16-lane slot), 8-deep clamped load pipeline.
// out[d] = (sum trans[src]) * rsqrt(clamp(ideg,1,K)) + bias
__global__ __launch_bounds__(256) void k2_gather(
        const uint16_t* __restrict__ trans,
        const int* __restrict__ ssrc, const int* __restrict__ row_start,
        const float* __restrict__ bias, const int* __restrict__ ideg,
        float* __restrict__ out, int ndst) {
    constexpr int U = 8;
    int gtid = blockIdx.x * blockDim.x + threadIdx.x;
    int wave = gtid >> 6;
    int lane = threadIdx.x & 63;
    int sub  = lane >> 4;          // dst slot 0..3
    int li   = lane & 15;          // 16B chunk within row
    int nwaves = (gridDim.x * blockDim.x) >> 6;

    float4 b0 = ((const float4*)bias)[li * 2];
    float4 b1 = ((const float4*)bias)[li * 2 + 1];

    for (int d0 = wave * 4; d0 < ndst; d0 += nwaves * 4) {
        int d = d0 + sub;
        int valid = (d < ndst);
        int s = 0, e = 0;
        if (valid) { s = row_start[d]; e = row_start[d + 1]; }
        int elast = (e > s) ? (e - 1) : 0;

        f32x2 acc[4];
#pragma unroll
        for (int k = 0; k < 4; ++k) acc[k] = (f32x2){0.f, 0.f};

        int idxv[U];
#pragma unroll
        for (int u = 0; u < U; ++u) idxv[u] = ssrc[min(s + u, elast)];

        int pos = s;
        while (__any(pos < e)) {
            uint4 v[U];
#pragma unroll
            for (int u = 0; u < U; ++u)
                v[u] = *(const uint4*)(trans + (size_t)idxv[u] * NDIM + li * 8);

            int npos = pos + U;
#pragma unroll
            for (int u = 0; u < U; ++u) idxv[u] = ssrc[min(npos + u, elast)];

#pragma unroll
            for (int u = 0; u < U; ++u) {
                if (pos + u < e) {
                    f32x2 t0 = {bf_lo(v[u].x), bf_hi(v[u].x)};
                    f32x2 t1 = {bf_lo(v[u].y), bf_hi(v[u].y)};
                    f32x2 t2 = {bf_lo(v[u].z), bf_hi(v[u].z)};
                    f32x2 t3 = {bf_lo(v[u].w), bf_hi(v[u].w)};
                    acc[0] += t0; acc[1] += t1; acc[2] += t2; acc[3] += t3;
                }
            }
            pos = npos;
        }

        if (valid) {
            float nrm = rsqrtf(fminf(fmaxf((float)ideg[d], 1.0f), KCLAMP));
            float4 o0, o1;
            o0.x = acc[0][0] * nrm + b0.x;
            o0.y = acc[0][1] * nrm + b0.y;
            o0.z = acc[1][0] * nrm + b0.z;
            o0.w = acc[1][1] * nrm + b0.w;
            o1.x = acc[2][0] * nrm + b1.x;
            o1.y = acc[2][1] * nrm + b1.y;
            o1.z = acc[3][0] * nrm + b1.z;
            o1.w = acc[3][1] * nrm + b1.w;
            ((float4*)out)[(size_t)d * (NDIM / 4) + li * 2]     = o0;
            ((float4*)out)[(size_t)d * (NDIM / 4) + li * 2 + 1] = o1;
        }
    }
}

// ---------------- fallbacks (workspace too small) ----------------
__global__ void k_rowptr(const int* __restrict__ sdst, int E,
                         int* __restrict__ row_start, int ndst) {
    int d = blockIdx.x * blockDim.x + threadIdx.x;
    if (d > ndst) return;
    int lo = 0, hi = E;
    while (lo < hi) {
        int mid = (lo + hi) >> 1;
        if (sdst[mid] < d) lo = mid + 1; else hi = mid;
    }
    row_start[d] = lo;
}

__global__ void k_agg_f32(const float* __restrict__ h, const int* __restrict__ odeg,
                          const int* __restrict__ ssrc, const int* __restrict__ row_start,
                          float* __restrict__ agg, int ndst) {
    int gtid = blockIdx.x * blockDim.x + threadIdx.x;
    int wave = gtid >> 6;
    int lane = threadIdx.x & 63;
    int nwaves = (gridDim.x * blockDim.x) >> 6;
    for (int d = wave; d < ndst; d += nwaves) {
        int s = row_start[d], e = row_start[d + 1];
        float a0 = 0.f, a1 = 0.f;
        for (int i = s; i < e; i++) {
            int s0 = ssrc[i];
            float nrm = rsqrtf(fmaxf((float)odeg[s0], 1.0f));
            float2 v = ((const float2*)h)[(size_t)s0 * (NDIM / 2) + lane];
            a0 += v.x * nrm;
            a1 += v.y * nrm;
        }
        float2 o; o.x = a0; o.y = a1;
        ((float2*)agg)[(size_t)d * (NDIM / 2) + lane] = o;
    }
}

__global__ __launch_bounds__(256) void k_gemm_f32(float* __restrict__ io,
                                                  const float* __restrict__ W,
                                                  const float* __restrict__ bias,
                                                  const int* __restrict__ ideg, int M) {
    __shared__ float Wsf[NDIM][NDIM];
    int tx = threadIdx.x;
    {
        const float4* Wv = (const float4*)W;
        float4* Wsv = (float4*)&Wsf[0][0];
        for (int i = tx; i < NDIM * NDIM / 4; i += 256) Wsv[i] = Wv[i];
    }
    __syncthreads();
    int cg = tx & 31, rg = tx >> 5;
    int r0 = blockIdx.x * 64 + rg * 8, c0 = cg * 4;
    float acc[8][4];
#pragma unroll
    for (int r = 0; r < 8; ++r)
#pragma unroll
        for (int c = 0; c < 4; ++c) acc[r][c] = 0.f;
    for (int k4 = 0; k4 < NDIM / 4; ++k4) {
        float4 wk0 = *(const float4*)&Wsf[4 * k4 + 0][c0];
        float4 wk1 = *(const float4*)&Wsf[4 * k4 + 1][c0];
        float4 wk2 = *(const float4*)&Wsf[4 * k4 + 2][c0];
        float4 wk3 = *(const float4*)&Wsf[4 * k4 + 3][c0];
#pragma unroll
        for (int r = 0; r < 8; ++r) {
            int row = r0 + r;
            if (row < M) {
                float4 a = ((const float4*)io)[(size_t)row * (NDIM / 4) + k4];
                acc[r][0] += a.x * wk0.x + a.y * wk1.x + a.z * wk2.x + a.w * wk3.x;
                acc[r][1] += a.x * wk0.y + a.y * wk1.y + a.z * wk2.y + a.w * wk3.y;
                acc[r][2] += a.x * wk0.z + a.y * wk1.z + a.z * wk2.z + a.w * wk3.z;
                acc[r][3] += a.x * wk0.w + a.y * wk1.w + a.z * wk2.w + a.w * wk3.w;
            }
        }
    }
    __syncthreads();
    float4 b = *(const float4*)&bias[c0];
#pragma unroll
    for (int r = 0; r < 8; ++r) {
        int row = r0 + r;
        if (row < M) {
            float nrm = rsqrtf(fminf(fmaxf((float)ideg[row], 1.0f), KCLAMP));
            float4 o;
            o.x = acc[r][0] * nrm + b.x;
            o.y = acc[r][1] * nrm + b.y;
            o.z = acc[r][2] * nrm + b.z;
            o.w = acc[r][3] * nrm + b.w;
            ((float4*)io)[(size_t)row * (NDIM / 4) + cg] = o;
        }
    }
}

extern "C" void kernel_launch(void* const* d_in, const int* in_sizes, int n_in,
                              void* d_out, int out_size, void* d_ws, size_t ws_size,
                              hipStream_t stream) {
    const float* h_src  = (const float*)d_in[0];
    const float* weight = (const float*)d_in[1];
    const float* bias   = (const float*)d_in[2];
    const int*   ssrc   = (const int*)d_in[3];
    const int*   sdst   = (const int*)d_in[4];
    const int*   odeg   = (const int*)d_in[5];
    const int*   ideg   = (const int*)d_in[6];
    float* out = (float*)d_out;

    int E    = in_sizes[3];
    int nsrc = in_sizes[0] / NDIM;
    int ndst = out_size / NDIM;

    // ws layout: [0,1MB) row_start ; [1MB, ..) trans (bf16 nsrc x 128)
    int*      row_start = (int*)d_ws;
    uint16_t* trans = (uint16_t*)((char*)d_ws + ((size_t)1 << 20));
    size_t need = ((size_t)1 << 20) + (size_t)nsrc * NDIM * 2;

    if (ws_size >= need) {
        int gemmBlocks = (nsrc + 127) / 128;
        int rpBlocks   = (ndst + 1 + 511) / 512;
        k1_gemm<<<gemmBlocks + rpBlocks, 512, 0, stream>>>(
            h_src, odeg, weight, trans, nsrc, sdst, E, row_start, ndst, gemmBlocks);
        k2_gather<<<2048, 256, 0, stream>>>(trans, ssrc, row_start, bias, ideg, out, ndst);
    } else {
        k_rowptr<<<(ndst + 1 + 255) / 256, 256, 0, stream>>>(sdst, E, row_start, ndst);
        k_agg_f32<<<2048, 256, 0, stream>>>(h_src, odeg, ssrc, row_start, out, ndst);
        k_gemm_f32<<<(ndst + 63) / 64, 256, 0, stream>>>(out, weight, bias, ideg, ndst);
    }
}